// Round 1
// baseline (356.050 us; speedup 1.0000x reference)
//
#include <hip/hip_runtime.h>
#include <cmath>

#define HH 96
#define WW 96
#define NPIX (HH * WW)
#define COEF 5.0f
#define BIGV 1.0e9f

#define TPB 256
#define ROWS_PER_BLOCK 4
#define F4_PER_ROW (NPIX / 4)            // 2304 float4 per output row
#define F4_PER_THREAD (F4_PER_ROW / TPB) // 9

// Kernel 1: per-pixel flat_ computation + init dmax slot. (unchanged, proven)
__global__ void k_flat(const float* __restrict__ img,
                       const float* __restrict__ thre,
                       const float* __restrict__ add,
                       float* __restrict__ flat_out,   // ws[0..NPIX)
                       float* __restrict__ dmax_slot)  // ws[NPIX]
{
    int t = blockIdx.x * blockDim.x + threadIdx.x;
    if (t == 0) *dmax_slot = 0.0f;  // int bits of 0.0f are 0
    if (t >= NPIX) return;
    int i = t / WW, j = t % WW;
    float v  = img[t];
    float th = thre[t];
    bool high = (v >= th);

    // 5x5 local max over "low" pixels (img < thre); 0 if none in window
    float mx = -BIGV;
    for (int di = -2; di <= 2; ++di) {
        int ni = i + di;
        if (ni < 0 || ni >= HH) continue;
        for (int dj = -2; dj <= 2; ++dj) {
            int nj = j + dj;
            if (nj < 0 || nj >= WW) continue;
            int n = ni * WW + nj;
            float nv = img[n];
            if (nv < thre[n]) mx = fmaxf(mx, nv);
        }
    }
    float maxlim = (mx <= -BIGV * 0.5f) ? 0.0f : mx;

    // 3x3 local min over "high" pixels (img >= thre); 0 if none in window
    float mn = BIGV;
    for (int di = -1; di <= 1; ++di) {
        int ni = i + di;
        if (ni < 0 || ni >= HH) continue;
        for (int dj = -1; dj <= 1; ++dj) {
            int nj = j + dj;
            if (nj < 0 || nj >= WW) continue;
            int n = ni * WW + nj;
            float nv = img[n];
            if (nv >= thre[n]) mn = fminf(mn, nv);
        }
    }
    float minlim = (mn >= BIGV * 0.5f) ? 0.0f : mn;

    float img_high = high ? v : 0.0f;
    float img_low  = high ? 0.0f : v;
    float ih = (img_high - minlim) / (1.0f - minlim + 1e-11f);
    float il = img_low / (maxlim + 1e-11f);
    flat_out[t] = ih + il + (high ? add[t] : 0.0f);
}

// Kernel 2: max over all edges of |flat_[r] - flat_[c]| (unchanged, proven)
__global__ void k_dmax(const float* __restrict__ flat_, float* dmax_slot)
{
    int t = blockIdx.x * blockDim.x + threadIdx.x;
    float d = 0.0f;
    if (t < NPIX) {
        int i = t / WW, j = t % WW;
        float fc = flat_[t];
        if (j + 1 < WW) d = fmaxf(d, fabsf(fc - flat_[t + 1]));
        if (i + 1 < HH) d = fmaxf(d, fabsf(fc - flat_[t + WW]));
    }
    for (int off = 32; off > 0; off >>= 1)
        d = fmaxf(d, __shfl_down(d, off, 64));
    if ((threadIdx.x & 63) == 0)
        atomicMax((int*)dmax_slot, __float_as_int(d));  // d >= 0: int-bit order ok
}

// Kernel 3 (NEW): fused zero-fill + scatter.
// One block per ROWS_PER_BLOCK output rows; each thread streams 9 float4/row,
// patching the row's <=4 nonzero entries in-register via static compares.
// Single 340 MB streaming write pass, 36 stores/wave-thread (amortizes wave
// startup), no second RMW pass over evicted lines.
__global__ __launch_bounds__(TPB) void k_write(const float* __restrict__ flat_,
                                               const float* __restrict__ dmax_slot,
                                               float4* __restrict__ out)
{
    const int row0 = blockIdx.x * ROWS_PER_BLOCK;
    const int tid  = threadIdx.x;
    const float inv_d = 1.0f / (*dmax_slot + 1e-11f);
    const float es = expf(-COEF);  // spatial term: 4-neighbor distance is always 1

    for (int r = 0; r < ROWS_PER_BLOCK; ++r) {
        const int t = row0 + r;
        const int i = t / WW, j = t % WW;
        const float fc = flat_[t];

        // Neighbor columns & normalized values; invalid -> col = -1 (never matches)
        int   nc[4];
        float nv[4];
        const int  off[4] = {-WW, WW, -1, 1};
        const bool ok[4]  = { i > 0, i < HH - 1, j > 0, j < WW - 1 };
        float row_sum = 0.0f;
        #pragma unroll
        for (int m = 0; m < 4; ++m) {
            if (ok[m]) {
                int n = t + off[m];
                float d = fabsf(fc - flat_[n]);
                float tot = es + expf(-COEF * d * inv_d);
                nc[m] = n; nv[m] = tot; row_sum += tot;
            } else {
                nc[m] = -1; nv[m] = 0.0f;
            }
        }
        const float inv_rs = 1.0f / row_sum;  // row_sum >= 2*exp(-5) > 0 always
        #pragma unroll
        for (int m = 0; m < 4; ++m) nv[m] *= inv_rs;

        const size_t rowbase = (size_t)t * F4_PER_ROW;
        #pragma unroll
        for (int k = 0; k < F4_PER_THREAD; ++k) {
            const int f4    = tid + k * TPB;
            const int cbase = f4 * 4;
            float4 v = make_float4(0.0f, 0.0f, 0.0f, 0.0f);
            #pragma unroll
            for (int m = 0; m < 4; ++m) {
                // nc[m] == -1 never matches (cbase >= 0): invalid neighbors inert
                v.x = (nc[m] == cbase + 0) ? nv[m] : v.x;
                v.y = (nc[m] == cbase + 1) ? nv[m] : v.y;
                v.z = (nc[m] == cbase + 2) ? nv[m] : v.z;
                v.w = (nc[m] == cbase + 3) ? nv[m] : v.w;
            }
            out[rowbase + f4] = v;
        }
    }
}

extern "C" void kernel_launch(void* const* d_in, const int* in_sizes, int n_in,
                              void* d_out, int out_size, void* d_ws, size_t ws_size,
                              hipStream_t stream)
{
    const float* img  = (const float*)d_in[0];
    const float* thre = (const float*)d_in[1];
    const float* add  = (const float*)d_in[2];
    float* out = (float*)d_out;
    float* ws  = (float*)d_ws;

    float* flat_ = ws;           // NPIX floats
    float* dmax  = ws + NPIX;    // 1 float

    const int pix_blocks = (NPIX + TPB - 1) / TPB;   // 36

    k_flat<<<pix_blocks, TPB, 0, stream>>>(img, thre, add, flat_, dmax);
    k_dmax<<<pix_blocks, TPB, 0, stream>>>(flat_, dmax);

    const int write_blocks = HH * WW / ROWS_PER_BLOCK;  // 2304
    k_write<<<write_blocks, TPB, 0, stream>>>(flat_, dmax, (float4*)out);
}

// Round 3
// 348.550 us; speedup vs baseline: 1.0215x; 1.0215x over previous
//
#include <hip/hip_runtime.h>
#include <cmath>

#define HH 96
#define WW 96
#define NPIX (HH * WW)
#define COEF 5.0f
#define BIGV 1.0e9f

#define TPB 256
#define F4_PER_ROW (NPIX / 4)            // 2304 float4 per output row
#define F4_PER_THREAD (F4_PER_ROW / TPB) // 9

// clang-native 4-float vector: required by __builtin_nontemporal_store
// (HIP's float4 is a class type the builtin rejects).
typedef float nat_f4 __attribute__((ext_vector_type(4)));

// Kernel 1: per-pixel flat_ computation + init dmax slot. (unchanged, proven)
__global__ void k_flat(const float* __restrict__ img,
                       const float* __restrict__ thre,
                       const float* __restrict__ add,
                       float* __restrict__ flat_out,   // ws[0..NPIX)
                       float* __restrict__ dmax_slot)  // ws[NPIX]
{
    int t = blockIdx.x * blockDim.x + threadIdx.x;
    if (t == 0) *dmax_slot = 0.0f;  // int bits of 0.0f are 0
    if (t >= NPIX) return;
    int i = t / WW, j = t % WW;
    float v  = img[t];
    float th = thre[t];
    bool high = (v >= th);

    // 5x5 local max over "low" pixels (img < thre); 0 if none in window
    float mx = -BIGV;
    for (int di = -2; di <= 2; ++di) {
        int ni = i + di;
        if (ni < 0 || ni >= HH) continue;
        for (int dj = -2; dj <= 2; ++dj) {
            int nj = j + dj;
            if (nj < 0 || nj >= WW) continue;
            int n = ni * WW + nj;
            float nv = img[n];
            if (nv < thre[n]) mx = fmaxf(mx, nv);
        }
    }
    float maxlim = (mx <= -BIGV * 0.5f) ? 0.0f : mx;

    // 3x3 local min over "high" pixels (img >= thre); 0 if none in window
    float mn = BIGV;
    for (int di = -1; di <= 1; ++di) {
        int ni = i + di;
        if (ni < 0 || ni >= HH) continue;
        for (int dj = -1; dj <= 1; ++dj) {
            int nj = j + dj;
            if (nj < 0 || nj >= WW) continue;
            int n = ni * WW + nj;
            float nv = img[n];
            if (nv >= thre[n]) mn = fminf(mn, nv);
        }
    }
    float minlim = (mn >= BIGV * 0.5f) ? 0.0f : mn;

    float img_high = high ? v : 0.0f;
    float img_low  = high ? 0.0f : v;
    float ih = (img_high - minlim) / (1.0f - minlim + 1e-11f);
    float il = img_low / (maxlim + 1e-11f);
    flat_out[t] = ih + il + (high ? add[t] : 0.0f);
}

// Kernel 2: max over all edges of |flat_[r] - flat_[c]| (unchanged, proven)
__global__ void k_dmax(const float* __restrict__ flat_, float* dmax_slot)
{
    int t = blockIdx.x * blockDim.x + threadIdx.x;
    float d = 0.0f;
    if (t < NPIX) {
        int i = t / WW, j = t % WW;
        float fc = flat_[t];
        if (j + 1 < WW) d = fmaxf(d, fabsf(fc - flat_[t + 1]));
        if (i + 1 < HH) d = fmaxf(d, fabsf(fc - flat_[t + WW]));
    }
    for (int off = 32; off > 0; off >>= 1)
        d = fmaxf(d, __shfl_down(d, off, 64));
    if ((threadIdx.x & 63) == 0)
        atomicMax((int*)dmax_slot, __float_as_int(d));  // d >= 0: int-bit order ok
}

// Kernel 3: fused zero-fill + scatter, v2 (fixed nt-store type).
// One block per output ROW (9216 blocks — k_zero-class parallelism), each
// thread streams 9 float4 with NONTEMPORAL stores (no L2 write-allocate for
// the 340 MB never-re-read output), patching the row's <=4 nonzero entries
// in-register via static compares.
__global__ __launch_bounds__(TPB) void k_write(const float* __restrict__ flat_,
                                               const float* __restrict__ dmax_slot,
                                               nat_f4* __restrict__ out)
{
    const int t   = blockIdx.x;     // output row index, 0..NPIX-1
    const int tid = threadIdx.x;
    const int i = t / WW, j = t % WW;
    const float fc = flat_[t];
    const float inv_d = 1.0f / (*dmax_slot + 1e-11f);
    const float es = expf(-COEF);   // spatial term: 4-neighbor distance always 1

    // Neighbor columns & normalized values; invalid -> col = -1 (never matches)
    int   nc[4];
    float nv[4];
    const int  off[4] = {-WW, WW, -1, 1};
    const bool ok[4]  = { i > 0, i < HH - 1, j > 0, j < WW - 1 };
    float row_sum = 0.0f;
    #pragma unroll
    for (int m = 0; m < 4; ++m) {
        if (ok[m]) {
            int n = t + off[m];
            float d = fabsf(fc - flat_[n]);
            float tot = es + expf(-COEF * d * inv_d);
            nc[m] = n; nv[m] = tot; row_sum += tot;
        } else {
            nc[m] = -1; nv[m] = 0.0f;
        }
    }
    const float inv_rs = 1.0f / row_sum;  // row_sum >= 2*exp(-5) > 0 always
    #pragma unroll
    for (int m = 0; m < 4; ++m) nv[m] *= inv_rs;

    const size_t rowbase = (size_t)t * F4_PER_ROW;
    #pragma unroll
    for (int k = 0; k < F4_PER_THREAD; ++k) {
        const int f4    = tid + k * TPB;
        const int cbase = f4 * 4;
        nat_f4 v = (nat_f4){0.0f, 0.0f, 0.0f, 0.0f};
        #pragma unroll
        for (int m = 0; m < 4; ++m) {
            // nc[m] == -1 never matches (cbase >= 0): invalid neighbors inert
            v.x = (nc[m] == cbase + 0) ? nv[m] : v.x;
            v.y = (nc[m] == cbase + 1) ? nv[m] : v.y;
            v.z = (nc[m] == cbase + 2) ? nv[m] : v.z;
            v.w = (nc[m] == cbase + 3) ? nv[m] : v.w;
        }
        __builtin_nontemporal_store(v, &out[rowbase + f4]);
    }
}

extern "C" void kernel_launch(void* const* d_in, const int* in_sizes, int n_in,
                              void* d_out, int out_size, void* d_ws, size_t ws_size,
                              hipStream_t stream)
{
    const float* img  = (const float*)d_in[0];
    const float* thre = (const float*)d_in[1];
    const float* add  = (const float*)d_in[2];
    float* out = (float*)d_out;
    float* ws  = (float*)d_ws;

    float* flat_ = ws;           // NPIX floats
    float* dmax  = ws + NPIX;    // 1 float

    const int pix_blocks = (NPIX + TPB - 1) / TPB;   // 36

    k_flat<<<pix_blocks, TPB, 0, stream>>>(img, thre, add, flat_, dmax);
    k_dmax<<<pix_blocks, TPB, 0, stream>>>(flat_, dmax);

    k_write<<<NPIX, TPB, 0, stream>>>(flat_, dmax, (nat_f4*)out);  // 1 block/row
}